// Round 9
// baseline (213.017 us; speedup 1.0000x reference)
//
#include <hip/hip_runtime.h>

#define B 4
#define N 512
#define M 8192
#define H 8
#define DH 16
#define DIM 128
#define J (M + N)          // 8704
#define LN10000_DIV8 1.1512925465f   // ln(10000)/8
#define LOG2E 1.44269504f

typedef _Float16 f16;
typedef _Float16 half4 __attribute__((ext_vector_type(4)));
typedef _Float16 half8 __attribute__((ext_vector_type(8)));
typedef __fp16 fp16x2 __attribute__((ext_vector_type(2)));
typedef float f32x4 __attribute__((ext_vector_type(4)));

#if __has_builtin(__builtin_amdgcn_exp2f)
#define EXP2(x) __builtin_amdgcn_exp2f(x)
#else
#define EXP2(x) exp2f(x)
#endif

union PK { fp16x2 v; unsigned int u; };

__device__ __forceinline__ half8 pack8(float a, float b, float c, float d,
                                       float e, float f, float g, float h) {
#if __has_builtin(__builtin_amdgcn_cvt_pkrtz)
    union { unsigned int u[4]; half8 h8; } r;
    PK p0, p1, p2, p3;
    p0.v = __builtin_amdgcn_cvt_pkrtz(a, b);
    p1.v = __builtin_amdgcn_cvt_pkrtz(c, d);
    p2.v = __builtin_amdgcn_cvt_pkrtz(e, f);
    p3.v = __builtin_amdgcn_cvt_pkrtz(g, h);
    r.u[0] = p0.u; r.u[1] = p1.u; r.u[2] = p2.u; r.u[3] = p3.u;
    return r.h8;
#else
    half8 r = { (f16)a, (f16)b, (f16)c, (f16)d, (f16)e, (f16)f, (f16)g, (f16)h };
    return r;
#endif
}

// ---- workspace layout ----
#define WS_KROT 0ull                              // f16 [32][J/32][512]  8,912,896 B (MFMA-frag tile order)
#define WS_VT   8912896ull                        // f16 [32][16][J]      8,912,896 B
#define WS_QROT 17825792ull                       // f16 [32][512][16]      524,288 B
#define WS_HV   18350080ull                       // f16 [2048][128]        524,288 B

union V4  { f16 h[4];  uint2 u; };

__device__ __forceinline__ half8 cvt8(const float* p) {
    float4 a = *(const float4*)p, b = *(const float4*)(p + 4);
    half8 h = { (f16)a.x, (f16)a.y, (f16)a.z, (f16)a.w,
                (f16)b.x, (f16)b.y, (f16)b.z, (f16)b.w };
    return h;
}

// ---------------------------------------------------------------------------
// Kernel 1: merged {proj GEMM (blocks 0..767)} + {prepKV (blocks 768..4863)}.
// DIAGNOSTIC ROUND: launched TWICE (idempotent - all writes are pure
// functions of inputs). new_total - 140.2 - 23 = prep_proj duration.
// ---------------------------------------------------------------------------
__global__ void __launch_bounds__(256) prep_proj_kernel(
    const f32x4* __restrict__ src, float4* __restrict__ dstv,
    f16* __restrict__ krot, f16* __restrict__ vt,
    const float* __restrict__ x, const float* __restrict__ g1,
    const float* __restrict__ b1, const float* __restrict__ wq,
    const float* __restrict__ wkv, f16* __restrict__ qrot)
{
    __shared__ __attribute__((aligned(16))) char smem[17408];

    if (blockIdx.x < 768) {                 // ================= proj =================
        f16 (*xnl)[136] = (f16 (*)[136])smem;   // [64][136] f16, 16B-aligned rows
        float* out_mem = (float*)dstv;
        int w = threadIdx.x >> 6, lane = threadIdx.x & 63;
        int id = blockIdx.x * 4 + w;
        int ttile = id & 127, ctile = id >> 7;
        int token0 = ttile * 16;
        int col = lane & 15, quad = lane >> 4;

        // ---- in-wave LN1 of this wave's 16 tokens into LDS ----
        {
            float g1a = g1[lane], g1b = g1[lane + 64];
            float b1a = b1[lane], b1b = b1[lane + 64];
            #pragma unroll 4
            for (int tt = 0; tt < 16; tt++) {
                int token = token0 + tt;
                float v0 = x[(size_t)token * DIM + lane];
                float v1 = x[(size_t)token * DIM + lane + 64];
                float s = v0 + v1;
                for (int off = 32; off; off >>= 1) s += __shfl_xor(s, off, 64);
                float mu = s * (1.0f / DIM);
                float d0 = v0 - mu, d1 = v1 - mu;
                float vs = d0 * d0 + d1 * d1;
                for (int off = 32; off; off >>= 1) vs += __shfl_xor(vs, off, 64);
                float rs = rsqrtf(vs * (1.0f / DIM) + 1e-5f);
                xnl[w * 16 + tt][lane]      = (f16)(d0 * rs * g1a + b1a);
                xnl[w * 16 + tt][lane + 64] = (f16)(d1 * rs * g1b + b1b);
            }
        }

        const float* wbase = (ctile < 8) ? (wq + (size_t)(ctile * 16 + col) * DIM)
                                         : (wkv + (size_t)((ctile - 8) * 16 + col) * DIM);
        const f16* arow = &xnl[w * 16 + col][quad * 8];

        f32x4 acc = {0.f, 0.f, 0.f, 0.f};
        #pragma unroll
        for (int kb = 0; kb < 4; kb++) {
            half8 a = *(const half8*)(arow + kb * 32);
            half8 wv = cvt8(wbase + kb * 32 + quad * 8);
            acc = __builtin_amdgcn_mfma_f32_16x16x32_f16(a, wv, acc, 0, 0, 0);
        }

        int e = col, r8 = e & 7;
        float f = __expf(-(float)r8 * LN10000_DIV8);
        int kt = ctile - 8;
        int head = (ctile < 8) ? ctile : (kt >> 1);
        int isV  = (ctile >= 8) ? (kt & 1) : 0;

        #pragma unroll
        for (int r = 0; r < 4; r++) {
            int tok = token0 + quad * 4 + r;
            int b = tok >> 9, i = tok & (N - 1);
            int bhh = b * H + head;
            float self = acc[r];
            float prt = __shfl_xor(self, 8, 64);  // partner dim e^8, same token

            if (ctile < 8) {                      // Q: rotary + scale (incl. log2e)
                float ang = (float)(M + i) * f;
                float sn, cs; __sincosf(ang, &sn, &cs);
                float rv = (self * cs + ((e < 8) ? -prt : prt) * sn) * (0.25f * LOG2E);
                qrot[((size_t)bhh * N + i) * 16 + e] = (f16)rv;
            } else if (!isV) {                    // K: fp32 append + repacked rotated fp16
                out_mem[((size_t)bhh * J + M + i) * 32 + e] = self;
                float ang = (float)(M + i) * f;
                float sn, cs; __sincosf(ang, &sn, &cs);
                float rv = self * cs + ((e < 8) ? -prt : prt) * sn;
                int jpos = M + i;
                int tilei = jpos >> 5, jj = jpos & 31;
                int col4 = (jj >> 3) * 4 + (jj & 3), frag = (jj >> 2) & 1;
                krot[(size_t)bhh * J * 16 + (size_t)tilei * 512 +
                     (e >> 2) * 128 + col4 * 8 + frag * 4 + (e & 3)] = (f16)rv;
            } else {                              // V: fp32 append + fp16 V^T
                out_mem[((size_t)bhh * J + M + i) * 32 + 16 + e] = self;
                vt[(size_t)bhh * 16 * J + (size_t)e * J + M + i] = (f16)self;
            }
        }
    } else {                                // ================ prepKV ================
        float (*tile)[33] = (float (*)[33])smem;
        int bid = blockIdx.x - 768;
        int bh = bid >> 7;
        int j0 = (bid & 127) * 64;
        int t = threadIdx.x;

        #pragma unroll
        for (int rep = 0; rep < 2; rep++) {
            int idx = t + rep * 256;
            int row = idx >> 3, c4 = idx & 7;
            f32x4 v = __builtin_nontemporal_load(src + ((size_t)bh * M + j0 + row) * 8 + c4);
            __builtin_nontemporal_store(v,
                (f32x4*)dstv + ((size_t)bh * J + j0 + row) * 8 + c4);
            tile[row][c4 * 4 + 0] = v[0]; tile[row][c4 * 4 + 1] = v[1];
            tile[row][c4 * 4 + 2] = v[2]; tile[row][c4 * 4 + 3] = v[3];
        }
        __syncthreads();

        if (t < 128) {                      // rotated K: 2 threads/row, 4 sincos each
            int row = t >> 1, rh = t & 1;
            int j = j0 + row;
            float lo4[4], hi4[4];
            #pragma unroll
            for (int i = 0; i < 4; i++) {
                int r = rh * 4 + i;
                float ang = (float)j * __expf(-(float)r * LN10000_DIV8);
                float sn, cs; __sincosf(ang, &sn, &cs);
                float lo = tile[row][r], hi = tile[row][r + 8];
                lo4[i] = lo * cs - hi * sn;
                hi4[i] = hi * cs + lo * sn;
            }
            int tilei = j >> 5, jj = j & 31;
            int col4 = (jj >> 3) * 4 + (jj & 3), frag = (jj >> 2) & 1;
            f16* base = krot + (size_t)bh * J * 16 + (size_t)tilei * 512 + col4 * 8 + frag * 4;
            V4 wl, wh;
            #pragma unroll
            for (int i = 0; i < 4; i++) { wl.h[i] = (f16)lo4[i]; wh.h[i] = (f16)hi4[i]; }
            *(uint2*)(base + rh * 128)       = wl.u;   // dims rh*4 .. rh*4+3
            *(uint2*)(base + (2 + rh) * 128) = wh.u;   // dims 8+rh*4 .. 8+rh*4+3
        }
        {                                   // V^T: dh-major, j contiguous
            int dh = t >> 4, c0 = (t & 15) * 4;
            V4 vv;
            #pragma unroll
            for (int i = 0; i < 4; i++) vv.h[i] = (f16)tile[c0 + i][16 + dh];
            *(uint2*)(vt + (size_t)bh * 16 * J + (size_t)dh * J + j0 + c0) = vv.u;
        }
    }
}

// ---------------------------------------------------------------------------
// Kernel 2: MFMA flash attention. DIAGNOSTIC ROUND: entire body runs TWICE
// inside one dispatch (pass loop; epilogue stores inside each pass so pass 0
// has side effects and cannot be DCE'd). One ~46us dispatch -> surfaces in
// rocprof top-5 with full pipe counters for the first time since R2.
// ---------------------------------------------------------------------------
__global__ void __launch_bounds__(1024) attn_kernel(
    const f16* __restrict__ krot, const f16* __restrict__ vt,
    const f16* __restrict__ qrot, f16* __restrict__ hvw)
{
    __shared__ float sacc[16][2][256];
    __shared__ float sl[16][2][16];
    int bh = blockIdx.x & 31;               // same-bh blocks -> same XCD
    int q0 = (blockIdx.x >> 5) * 32;
    int wave = threadIdx.x >> 6, lane = threadIdx.x & 63;
    int col = lane & 15, quad = lane >> 4;

    const f16* vb = vt + (size_t)bh * 16 * J + (size_t)col * J;
    half4 qfa = *(const half4*)(qrot + ((size_t)bh * N + q0 + col) * 16 + quad * 4);
    half4 qfb = *(const half4*)(qrot + ((size_t)bh * N + q0 + 16 + col) * 16 + quad * 4);

    for (int pass = 0; pass < 2; ++pass) {
        int jstart = wave * (J / 16);       // 544 = 17 iters of 32 keys
        const f16* kptr = krot + (size_t)bh * J * 16 + (size_t)jstart * 16 + lane * 8;
        const f16* vptr = vb + jstart + quad * 8;

        f32x4 acca = {0.f, 0.f, 0.f, 0.f};
        f32x4 accb = {0.f, 0.f, 0.f, 0.f};
        f32x4 accla = {0.f, 0.f, 0.f, 0.f};
        f32x4 acclb = {0.f, 0.f, 0.f, 0.f};
        const f32x4 zero = {0.f, 0.f, 0.f, 0.f};
        const half8 ones = { (f16)1.f, (f16)1.f, (f16)1.f, (f16)1.f,
                             (f16)1.f, (f16)1.f, (f16)1.f, (f16)1.f };

        half8 kf8 = *(const half8*)kptr;    // prologue loads (iter 0)
        half8 vf  = *(const half8*)vptr;

        #pragma unroll 2
        for (int it = 0; it < 17; ++it) {
            half8 kc = kf8, vc = vf;
            if (it < 16) {                  // prefetch it+1 before computing it
                kptr += 512; vptr += 32;
                kf8 = *(const half8*)kptr;
                vf  = *(const half8*)vptr;
            }
            half4 kf0 = __builtin_shufflevector(kc, kc, 0, 1, 2, 3);
            half4 kf1 = __builtin_shufflevector(kc, kc, 4, 5, 6, 7);
            f32x4 s0a = __builtin_amdgcn_mfma_f32_16x16x16f16(kf0, qfa, zero, 0, 0, 0);
            f32x4 s1a = __builtin_amdgcn_mfma_f32_16x16x16f16(kf1, qfa, zero, 0, 0, 0);
            f32x4 s0b = __builtin_amdgcn_mfma_f32_16x16x16f16(kf0, qfb, zero, 0, 0, 0);
            f32x4 s1b = __builtin_amdgcn_mfma_f32_16x16x16f16(kf1, qfb, zero, 0, 0, 0);

            float a0 = EXP2(s0a[0]), a1 = EXP2(s0a[1]), a2 = EXP2(s0a[2]), a3 = EXP2(s0a[3]);
            float a4 = EXP2(s1a[0]), a5 = EXP2(s1a[1]), a6 = EXP2(s1a[2]), a7 = EXP2(s1a[3]);
            float b0 = EXP2(s0b[0]), b1 = EXP2(s0b[1]), b2 = EXP2(s0b[2]), b3 = EXP2(s0b[3]);
            float b4 = EXP2(s1b[0]), b5 = EXP2(s1b[1]), b6 = EXP2(s1b[2]), b7 = EXP2(s1b[3]);
            half8 pfa = pack8(a0, a1, a2, a3, a4, a5, a6, a7);
            half8 pfb = pack8(b0, b1, b2, b3, b4, b5, b6, b7);
            acca  = __builtin_amdgcn_mfma_f32_16x16x32_f16(pfa, vc,   acca,  0, 0, 0);
            accla = __builtin_amdgcn_mfma_f32_16x16x32_f16(pfa, ones, accla, 0, 0, 0);
            accb  = __builtin_amdgcn_mfma_f32_16x16x32_f16(pfb, vc,   accb,  0, 0, 0);
            acclb = __builtin_amdgcn_mfma_f32_16x16x32_f16(pfb, ones, acclb, 0, 0, 0);
        }

        if (col == 0) {                     // l row-sums live in every col of accl*
            #pragma unroll
            for (int r = 0; r < 4; r++) {
                sl[wave][0][quad * 4 + r] = accla[r];
                sl[wave][1][quad * 4 + r] = acclb[r];
            }
        }
        #pragma unroll
        for (int r = 0; r < 4; r++) {
            sacc[wave][0][(quad * 4 + r) * 16 + col] = acca[r];
            sacc[wave][1][(quad * 4 + r) * 16 + col] = accb[r];
        }
        __syncthreads();

        if (threadIdx.x < 512) {            // 512 outputs -> 512 threads (8 waves)
            int t = threadIdx.x;
            int qt = t >> 8, ql = (t >> 4) & 15, c = t & 15;
            float o = 0.f, lt = 0.f;
            #pragma unroll
            for (int w = 0; w < 16; w++) {
                o  += sacc[w][qt][ql * 16 + c];
                lt += sl[w][qt][ql];
            }
            int b = bh >> 3, h = bh & 7;
            hvw[((size_t)(b * N) + q0 + qt * 16 + ql) * DIM + h * DH + c] = (f16)(o / lt);
        }
        __syncthreads();                    // pass 1 overwrites sacc/sl after readers done
    }
}

// ---------------------------------------------------------------------------
// Kernel 3: fused residual + LN2 + MFMA out-proj + residual.
// ---------------------------------------------------------------------------
__global__ void __launch_bounds__(256) final_kernel(
    const f16* __restrict__ hvw, const float* __restrict__ x,
    const float* __restrict__ wout, const float* __restrict__ bout,
    const float* __restrict__ g2, const float* __restrict__ b2v,
    float* __restrict__ out)
{
    __shared__ f16 xn2[16][136];
    __shared__ float hres[16][132];
    int token0 = (blockIdx.x >> 1) * 16;
    int half = blockIdx.x & 1;
    int wave = threadIdx.x >> 6, lane = threadIdx.x & 63;

    #pragma unroll
    for (int tt = 0; tt < 4; tt++) {
        int tl = wave * 4 + tt;
        int token = token0 + tl;
        float h0 = (float)hvw[(size_t)token * DIM + lane]      + x[(size_t)token * DIM + lane];
        float h1 = (float)hvw[(size_t)token * DIM + lane + 64] + x[(size_t)token * DIM + lane + 64];
        float s = h0 + h1;
        for (int off = 32; off; off >>= 1) s += __shfl_xor(s, off, 64);
        float mu = s * (1.0f / DIM);
        float d0 = h0 - mu, d1 = h1 - mu;
        float vs = d0 * d0 + d1 * d1;
        for (int off = 32; off; off >>= 1) vs += __shfl_xor(vs, off, 64);
        float rs = rsqrtf(vs * (1.0f / DIM) + 1e-5f);
        xn2[tl][lane]      = (f16)(d0 * rs * g2[lane]      + b2v[lane]);
        xn2[tl][lane + 64] = (f16)(d1 * rs * g2[lane + 64] + b2v[lane + 64]);
        hres[tl][lane] = h0; hres[tl][lane + 64] = h1;
    }
    __syncthreads();

    int col = lane & 15, quad = lane >> 4;
    int ct = half * 4 + wave;               // this block's 4 col-tiles
    int cg = ct * 16 + col;
    const float* wrow = wout + (size_t)cg * DIM;
    f32x4 acc = {0.f, 0.f, 0.f, 0.f};
    #pragma unroll
    for (int kb = 0; kb < 4; kb++) {
        half8 a = *(const half8*)(&xn2[col][kb * 32 + quad * 8]);
        half8 w = cvt8(wrow + kb * 32 + quad * 8);
        acc = __builtin_amdgcn_mfma_f32_16x16x32_f16(a, w, acc, 0, 0, 0);
    }
    float bo = bout[cg];
    #pragma unroll
    for (int r = 0; r < 4; r++) {
        int tl = quad * 4 + r;
        out[(size_t)(token0 + tl) * DIM + cg] = acc[r] + bo + hres[tl][cg];
    }
}

// ===========================================================================
extern "C" void kernel_launch(void* const* d_in, const int* in_sizes, int n_in,
                              void* d_out, int out_size, void* d_ws, size_t ws_size,
                              hipStream_t stream)
{
    const float* x      = (const float*)d_in[0];
    const float* mem_kv = (const float*)d_in[1];
    const float* wq     = (const float*)d_in[2];
    const float* wkv    = (const float*)d_in[3];
    const float* wout   = (const float*)d_in[4];
    const float* bout   = (const float*)d_in[5];
    const float* g1     = (const float*)d_in[6];
    const float* b1     = (const float*)d_in[7];
    const float* g2     = (const float*)d_in[8];
    const float* b2     = (const float*)d_in[9];

    float* out = (float*)d_out;
    float* out_mem = out + (size_t)B * N * DIM;

    f16* krot = (f16*)((char*)d_ws + WS_KROT);
    f16* vt   = (f16*)((char*)d_ws + WS_VT);
    f16* qrot = (f16*)((char*)d_ws + WS_QROT);
    f16* hvw  = (f16*)((char*)d_ws + WS_HV);

    // DIAGNOSTIC: prep_proj launched twice (idempotent).
    hipLaunchKernelGGL(prep_proj_kernel, dim3(4864), dim3(256), 0, stream,
                       (const f32x4*)mem_kv, (float4*)out_mem, krot, vt,
                       x, g1, b1, wq, wkv, qrot);
    hipLaunchKernelGGL(prep_proj_kernel, dim3(4864), dim3(256), 0, stream,
                       (const f32x4*)mem_kv, (float4*)out_mem, krot, vt,
                       x, g1, b1, wq, wkv, qrot);
    hipLaunchKernelGGL(attn_kernel, dim3(512), dim3(1024), 0, stream,
                       krot, vt, qrot, hvw);
    hipLaunchKernelGGL(final_kernel, dim3(256), dim3(256), 0, stream,
                       hvw, x, wout, bout, g2, b2, out);
}

// Round 10
// 146.774 us; speedup vs baseline: 1.4513x; 1.4513x over previous
//
#include <hip/hip_runtime.h>

#define B 4
#define N 512
#define M 8192
#define H 8
#define DH 16
#define DIM 128
#define J (M + N)          // 8704
#define LN10000_DIV8 1.1512925465f   // ln(10000)/8
#define LOG2E 1.44269504f

typedef _Float16 f16;
typedef _Float16 half4 __attribute__((ext_vector_type(4)));
typedef _Float16 half8 __attribute__((ext_vector_type(8)));
typedef __fp16 fp16x2 __attribute__((ext_vector_type(2)));
typedef float f32x4 __attribute__((ext_vector_type(4)));

#if __has_builtin(__builtin_amdgcn_exp2f)
#define EXP2(x) __builtin_amdgcn_exp2f(x)
#else
#define EXP2(x) exp2f(x)
#endif

union PK { fp16x2 v; unsigned int u; };

__device__ __forceinline__ half8 pack8(float a, float b, float c, float d,
                                       float e, float f, float g, float h) {
#if __has_builtin(__builtin_amdgcn_cvt_pkrtz)
    union { unsigned int u[4]; half8 h8; } r;
    PK p0, p1, p2, p3;
    p0.v = __builtin_amdgcn_cvt_pkrtz(a, b);
    p1.v = __builtin_amdgcn_cvt_pkrtz(c, d);
    p2.v = __builtin_amdgcn_cvt_pkrtz(e, f);
    p3.v = __builtin_amdgcn_cvt_pkrtz(g, h);
    r.u[0] = p0.u; r.u[1] = p1.u; r.u[2] = p2.u; r.u[3] = p3.u;
    return r.h8;
#else
    half8 r = { (f16)a, (f16)b, (f16)c, (f16)d, (f16)e, (f16)f, (f16)g, (f16)h };
    return r;
#endif
}

// ---- workspace layout ----
#define WS_KROT 0ull                              // f16 [32][J/32][512]  8,912,896 B (MFMA-frag tile order)
#define WS_VT   8912896ull                        // f16 [32][16][J]      8,912,896 B
#define WS_QROT 17825792ull                       // f16 [32][512][16]      524,288 B
#define WS_HV   18350080ull                       // f16 [2048][128]        524,288 B

union V4  { f16 h[4];  uint2 u; };

__device__ __forceinline__ half8 cvt8(const float* p) {
    float4 a = *(const float4*)p, b = *(const float4*)(p + 4);
    half8 h = { (f16)a.x, (f16)a.y, (f16)a.z, (f16)a.w,
                (f16)b.x, (f16)b.y, (f16)b.z, (f16)b.w };
    return h;
}

// ---------------------------------------------------------------------------
// Kernel 1: merged {proj GEMM (blocks 0..767)} + {prepKV (blocks 768..4863)}.
// proj computes its OWN LN1 per wave (wave-coherent, no barrier).
// ---------------------------------------------------------------------------
__global__ void __launch_bounds__(256) prep_proj_kernel(
    const f32x4* __restrict__ src, float4* __restrict__ dstv,
    f16* __restrict__ krot, f16* __restrict__ vt,
    const float* __restrict__ x, const float* __restrict__ g1,
    const float* __restrict__ b1, const float* __restrict__ wq,
    const float* __restrict__ wkv, f16* __restrict__ qrot)
{
    __shared__ __attribute__((aligned(16))) char smem[17408];

    if (blockIdx.x < 768) {                 // ================= proj =================
        f16 (*xnl)[136] = (f16 (*)[136])smem;   // [64][136] f16, 16B-aligned rows
        float* out_mem = (float*)dstv;
        int w = threadIdx.x >> 6, lane = threadIdx.x & 63;
        int id = blockIdx.x * 4 + w;
        int ttile = id & 127, ctile = id >> 7;
        int token0 = ttile * 16;
        int col = lane & 15, quad = lane >> 4;

        // ---- in-wave LN1 of this wave's 16 tokens into LDS ----
        {
            float g1a = g1[lane], g1b = g1[lane + 64];
            float b1a = b1[lane], b1b = b1[lane + 64];
            #pragma unroll 4
            for (int tt = 0; tt < 16; tt++) {
                int token = token0 + tt;
                float v0 = x[(size_t)token * DIM + lane];
                float v1 = x[(size_t)token * DIM + lane + 64];
                float s = v0 + v1;
                for (int off = 32; off; off >>= 1) s += __shfl_xor(s, off, 64);
                float mu = s * (1.0f / DIM);
                float d0 = v0 - mu, d1 = v1 - mu;
                float vs = d0 * d0 + d1 * d1;
                for (int off = 32; off; off >>= 1) vs += __shfl_xor(vs, off, 64);
                float rs = rsqrtf(vs * (1.0f / DIM) + 1e-5f);
                xnl[w * 16 + tt][lane]      = (f16)(d0 * rs * g1a + b1a);
                xnl[w * 16 + tt][lane + 64] = (f16)(d1 * rs * g1b + b1b);
            }
        }

        const float* wbase = (ctile < 8) ? (wq + (size_t)(ctile * 16 + col) * DIM)
                                         : (wkv + (size_t)((ctile - 8) * 16 + col) * DIM);
        const f16* arow = &xnl[w * 16 + col][quad * 8];

        f32x4 acc = {0.f, 0.f, 0.f, 0.f};
        #pragma unroll
        for (int kb = 0; kb < 4; kb++) {
            half8 a = *(const half8*)(arow + kb * 32);
            half8 wv = cvt8(wbase + kb * 32 + quad * 8);
            acc = __builtin_amdgcn_mfma_f32_16x16x32_f16(a, wv, acc, 0, 0, 0);
        }

        int e = col, r8 = e & 7;
        float f = __expf(-(float)r8 * LN10000_DIV8);
        int kt = ctile - 8;
        int head = (ctile < 8) ? ctile : (kt >> 1);
        int isV  = (ctile >= 8) ? (kt & 1) : 0;

        #pragma unroll
        for (int r = 0; r < 4; r++) {
            int tok = token0 + quad * 4 + r;
            int b = tok >> 9, i = tok & (N - 1);
            int bhh = b * H + head;
            float self = acc[r];
            float prt = __shfl_xor(self, 8, 64);  // partner dim e^8, same token

            if (ctile < 8) {                      // Q: rotary + scale (incl. log2e)
                float ang = (float)(M + i) * f;
                float sn, cs; __sincosf(ang, &sn, &cs);
                float rv = (self * cs + ((e < 8) ? -prt : prt) * sn) * (0.25f * LOG2E);
                qrot[((size_t)bhh * N + i) * 16 + e] = (f16)rv;
            } else if (!isV) {                    // K: fp32 append + repacked rotated fp16
                out_mem[((size_t)bhh * J + M + i) * 32 + e] = self;
                float ang = (float)(M + i) * f;
                float sn, cs; __sincosf(ang, &sn, &cs);
                float rv = self * cs + ((e < 8) ? -prt : prt) * sn;
                int jpos = M + i;
                int tilei = jpos >> 5, jj = jpos & 31;
                int col4 = (jj >> 3) * 4 + (jj & 3), frag = (jj >> 2) & 1;
                krot[(size_t)bhh * J * 16 + (size_t)tilei * 512 +
                     (e >> 2) * 128 + col4 * 8 + frag * 4 + (e & 3)] = (f16)rv;
            } else {                              // V: fp32 append + fp16 V^T
                out_mem[((size_t)bhh * J + M + i) * 32 + 16 + e] = self;
                vt[(size_t)bhh * 16 * J + (size_t)e * J + M + i] = (f16)self;
            }
        }
    } else {                                // ================ prepKV ================
        float (*tile)[33] = (float (*)[33])smem;
        int bid = blockIdx.x - 768;
        int bh = bid >> 7;
        int j0 = (bid & 127) * 64;
        int t = threadIdx.x;

        #pragma unroll
        for (int rep = 0; rep < 2; rep++) {
            int idx = t + rep * 256;
            int row = idx >> 3, c4 = idx & 7;
            f32x4 v = __builtin_nontemporal_load(src + ((size_t)bh * M + j0 + row) * 8 + c4);
            __builtin_nontemporal_store(v,
                (f32x4*)dstv + ((size_t)bh * J + j0 + row) * 8 + c4);
            tile[row][c4 * 4 + 0] = v[0]; tile[row][c4 * 4 + 1] = v[1];
            tile[row][c4 * 4 + 2] = v[2]; tile[row][c4 * 4 + 3] = v[3];
        }
        __syncthreads();

        if (t < 128) {                      // rotated K: 2 threads/row, 4 sincos each
            int row = t >> 1, rh = t & 1;
            int j = j0 + row;
            float lo4[4], hi4[4];
            #pragma unroll
            for (int i = 0; i < 4; i++) {
                int r = rh * 4 + i;
                float ang = (float)j * __expf(-(float)r * LN10000_DIV8);
                float sn, cs; __sincosf(ang, &sn, &cs);
                float lo = tile[row][r], hi = tile[row][r + 8];
                lo4[i] = lo * cs - hi * sn;
                hi4[i] = hi * cs + lo * sn;
            }
            int tilei = j >> 5, jj = j & 31;
            int col4 = (jj >> 3) * 4 + (jj & 3), frag = (jj >> 2) & 1;
            f16* base = krot + (size_t)bh * J * 16 + (size_t)tilei * 512 + col4 * 8 + frag * 4;
            V4 wl, wh;
            #pragma unroll
            for (int i = 0; i < 4; i++) { wl.h[i] = (f16)lo4[i]; wh.h[i] = (f16)hi4[i]; }
            *(uint2*)(base + rh * 128)       = wl.u;   // dims rh*4 .. rh*4+3
            *(uint2*)(base + (2 + rh) * 128) = wh.u;   // dims 8+rh*4 .. 8+rh*4+3
        }
        {                                   // V^T: dh-major, j contiguous
            int dh = t >> 4, c0 = (t & 15) * 4;
            V4 vv;
            #pragma unroll
            for (int i = 0; i < 4; i++) vv.h[i] = (f16)tile[c0 + i][16 + dh];
            *(uint2*)(vt + (size_t)bh * 16 * J + (size_t)dh * J + j0 + c0) = vv.u;
        }
    }
}

// ---------------------------------------------------------------------------
// Kernel 2: MFMA flash attention, demand-halved layout.
// R9 counters: attn is a beyond-L2 fetch stream (3.1 TB/s, all pipes <30%).
// Fix: 64 q-rows per block (4 q-tiles per wave) -> only 8 blocks share each
// bh's 557KB K/V (was 16), halving L2-miss demand (285->142MB). Grid =
// 256 blocks (32 bh x 8 qchunks; bh in low 5 bits keeps same-bh on one XCD)
// x 512 thr = 8 waves; wave covers J/8 = 1088 keys (34 iters) for 4 q-tiles,
// so each K/V fragment feeds 4 q-tiles. 1 block/CU, all 256 CUs busy.
// Softmax denominator on MFMA pipe via all-ones B operand; no-max exp2.
// ---------------------------------------------------------------------------
__global__ void __launch_bounds__(512, 2) attn_kernel(
    const f16* __restrict__ krot, const f16* __restrict__ vt,
    const f16* __restrict__ qrot, f16* __restrict__ hvw)
{
    __shared__ float sacc[8][4][256];       // 32 KB
    __shared__ float sl[8][4][16];          // 2 KB
    int bh = blockIdx.x & 31;               // same-bh blocks -> same XCD
    int q0 = (blockIdx.x >> 5) * 64;        // 8 qchunks of 64 rows
    int wave = threadIdx.x >> 6, lane = threadIdx.x & 63;
    int col = lane & 15, quad = lane >> 4;

    const f16* vb = vt + (size_t)bh * 16 * J + (size_t)col * J;
    const f16* qb = qrot + ((size_t)bh * N + q0 + col) * 16 + quad * 4;
    half4 qf0 = *(const half4*)(qb);
    half4 qf1 = *(const half4*)(qb + 16 * 16);
    half4 qf2 = *(const half4*)(qb + 32 * 16);
    half4 qf3 = *(const half4*)(qb + 48 * 16);

    int jstart = wave * (J / 8);            // 1088 = 34 iters of 32 keys
    const f16* kptr = krot + (size_t)bh * J * 16 + (size_t)jstart * 16 + lane * 8;
    const f16* vptr = vb + jstart + quad * 8;

    f32x4 acc0 = {0.f,0.f,0.f,0.f}, acc1 = {0.f,0.f,0.f,0.f};
    f32x4 acc2 = {0.f,0.f,0.f,0.f}, acc3 = {0.f,0.f,0.f,0.f};
    f32x4 accl0 = {0.f,0.f,0.f,0.f}, accl1 = {0.f,0.f,0.f,0.f};
    f32x4 accl2 = {0.f,0.f,0.f,0.f}, accl3 = {0.f,0.f,0.f,0.f};
    const f32x4 zero = {0.f, 0.f, 0.f, 0.f};
    const half8 ones = { (f16)1.f, (f16)1.f, (f16)1.f, (f16)1.f,
                         (f16)1.f, (f16)1.f, (f16)1.f, (f16)1.f };

    for (int it = 0; it < 34; ++it) {
        half8 kf8 = *(const half8*)kptr;
        half8 vf  = *(const half8*)vptr;
        kptr += 512; vptr += 32;
        half4 kf0 = __builtin_shufflevector(kf8, kf8, 0, 1, 2, 3);
        half4 kf1 = __builtin_shufflevector(kf8, kf8, 4, 5, 6, 7);

#define QTILE(QF, ACC, ACCL)                                                     \
        {                                                                        \
            f32x4 s0 = __builtin_amdgcn_mfma_f32_16x16x16f16(kf0, QF, zero, 0, 0, 0); \
            f32x4 s1 = __builtin_amdgcn_mfma_f32_16x16x16f16(kf1, QF, zero, 0, 0, 0); \
            float e0 = EXP2(s0[0]), e1 = EXP2(s0[1]), e2 = EXP2(s0[2]), e3 = EXP2(s0[3]); \
            float e4 = EXP2(s1[0]), e5 = EXP2(s1[1]), e6 = EXP2(s1[2]), e7 = EXP2(s1[3]); \
            half8 pf = pack8(e0, e1, e2, e3, e4, e5, e6, e7);                    \
            ACC  = __builtin_amdgcn_mfma_f32_16x16x32_f16(pf, vf,   ACC,  0, 0, 0); \
            ACCL = __builtin_amdgcn_mfma_f32_16x16x32_f16(pf, ones, ACCL, 0, 0, 0); \
        }
        QTILE(qf0, acc0, accl0)
        QTILE(qf1, acc1, accl1)
        QTILE(qf2, acc2, accl2)
        QTILE(qf3, acc3, accl3)
#undef QTILE
    }

    if (col == 0) {                         // l row-sums live in every col of accl*
        #pragma unroll
        for (int r = 0; r < 4; r++) {
            sl[wave][0][quad * 4 + r] = accl0[r];
            sl[wave][1][quad * 4 + r] = accl1[r];
            sl[wave][2][quad * 4 + r] = accl2[r];
            sl[wave][3][quad * 4 + r] = accl3[r];
        }
    }
    #pragma unroll
    for (int r = 0; r < 4; r++) {
        sacc[wave][0][(quad * 4 + r) * 16 + col] = acc0[r];
        sacc[wave][1][(quad * 4 + r) * 16 + col] = acc1[r];
        sacc[wave][2][(quad * 4 + r) * 16 + col] = acc2[r];
        sacc[wave][3][(quad * 4 + r) * 16 + col] = acc3[r];
    }
    __syncthreads();

    {                                       // 1024 outputs over 512 threads
        int b = bh >> 3, h = bh & 7;
        #pragma unroll
        for (int o = threadIdx.x; o < 1024; o += 512) {
            int qt = o >> 8, ql = (o >> 4) & 15, c = o & 15;
            float os = 0.f, lt = 0.f;
            #pragma unroll
            for (int w = 0; w < 8; w++) {
                os += sacc[w][qt][ql * 16 + c];
                lt += sl[w][qt][ql];
            }
            hvw[((size_t)(b * N) + q0 + qt * 16 + ql) * DIM + h * DH + c] = (f16)(os / lt);
        }
    }
}

// ---------------------------------------------------------------------------
// Kernel 3: fused residual + LN2 + MFMA out-proj + residual.
// grid = 256 blocks (16 tokens, 4 of 8 col-tiles each), 256 thr = 4 waves.
// ---------------------------------------------------------------------------
__global__ void __launch_bounds__(256) final_kernel(
    const f16* __restrict__ hvw, const float* __restrict__ x,
    const float* __restrict__ wout, const float* __restrict__ bout,
    const float* __restrict__ g2, const float* __restrict__ b2v,
    float* __restrict__ out)
{
    __shared__ f16 xn2[16][136];
    __shared__ float hres[16][132];
    int token0 = (blockIdx.x >> 1) * 16;
    int half = blockIdx.x & 1;
    int wave = threadIdx.x >> 6, lane = threadIdx.x & 63;

    #pragma unroll
    for (int tt = 0; tt < 4; tt++) {
        int tl = wave * 4 + tt;
        int token = token0 + tl;
        float h0 = (float)hvw[(size_t)token * DIM + lane]      + x[(size_t)token * DIM + lane];
        float h1 = (float)hvw[(size_t)token * DIM + lane + 64] + x[(size_t)token * DIM + lane + 64];
        float s = h0 + h1;
        for (int off = 32; off; off >>= 1) s += __shfl_xor(s, off, 64);
        float mu = s * (1.0f / DIM);
        float d0 = h0 - mu, d1 = h1 - mu;
        float vs = d0 * d0 + d1 * d1;
        for (int off = 32; off; off >>= 1) vs += __shfl_xor(vs, off, 64);
        float rs = rsqrtf(vs * (1.0f / DIM) + 1e-5f);
        xn2[tl][lane]      = (f16)(d0 * rs * g2[lane]      + b2v[lane]);
        xn2[tl][lane + 64] = (f16)(d1 * rs * g2[lane + 64] + b2v[lane + 64]);
        hres[tl][lane] = h0; hres[tl][lane + 64] = h1;
    }
    __syncthreads();

    int col = lane & 15, quad = lane >> 4;
    int ct = half * 4 + wave;               // this block's 4 col-tiles
    int cg = ct * 16 + col;
    const float* wrow = wout + (size_t)cg * DIM;
    f32x4 acc = {0.f, 0.f, 0.f, 0.f};
    #pragma unroll
    for (int kb = 0; kb < 4; kb++) {
        half8 a = *(const half8*)(&xn2[col][kb * 32 + quad * 8]);
        half8 w = cvt8(wrow + kb * 32 + quad * 8);
        acc = __builtin_amdgcn_mfma_f32_16x16x32_f16(a, w, acc, 0, 0, 0);
    }
    float bo = bout[cg];
    #pragma unroll
    for (int r = 0; r < 4; r++) {
        int tl = quad * 4 + r;
        out[(size_t)(token0 + tl) * DIM + cg] = acc[r] + bo + hres[tl][cg];
    }
}

// ===========================================================================
extern "C" void kernel_launch(void* const* d_in, const int* in_sizes, int n_in,
                              void* d_out, int out_size, void* d_ws, size_t ws_size,
                              hipStream_t stream)
{
    const float* x      = (const float*)d_in[0];
    const float* mem_kv = (const float*)d_in[1];
    const float* wq     = (const float*)d_in[2];
    const float* wkv    = (const float*)d_in[3];
    const float* wout   = (const float*)d_in[4];
    const float* bout   = (const float*)d_in[5];
    const float* g1     = (const float*)d_in[6];
    const float* b1     = (const float*)d_in[7];
    const float* g2     = (const float*)d_in[8];
    const float* b2     = (const float*)d_in[9];

    float* out = (float*)d_out;
    float* out_mem = out + (size_t)B * N * DIM;

    f16* krot = (f16*)((char*)d_ws + WS_KROT);
    f16* vt   = (f16*)((char*)d_ws + WS_VT);
    f16* qrot = (f16*)((char*)d_ws + WS_QROT);
    f16* hvw  = (f16*)((char*)d_ws + WS_HV);

    hipLaunchKernelGGL(prep_proj_kernel, dim3(4864), dim3(256), 0, stream,
                       (const f32x4*)mem_kv, (float4*)out_mem, krot, vt,
                       x, g1, b1, wq, wkv, qrot);
    hipLaunchKernelGGL(attn_kernel, dim3(256), dim3(512), 0, stream,
                       krot, vt, qrot, hvw);
    hipLaunchKernelGGL(final_kernel, dim3(256), dim3(256), 0, stream,
                       hvw, x, wout, bout, g2, b2, out);
}

// Round 11
// 143.447 us; speedup vs baseline: 1.4850x; 1.0232x over previous
//
#include <hip/hip_runtime.h>

#define B 4
#define N 512
#define M 8192
#define H 8
#define DH 16
#define DIM 128
#define J (M + N)          // 8704
#define LN10000_DIV8 1.1512925465f   // ln(10000)/8
#define LOG2E 1.44269504f

typedef _Float16 f16;
typedef _Float16 half4 __attribute__((ext_vector_type(4)));
typedef _Float16 half8 __attribute__((ext_vector_type(8)));
typedef __fp16 fp16x2 __attribute__((ext_vector_type(2)));
typedef float f32x4 __attribute__((ext_vector_type(4)));

#if __has_builtin(__builtin_amdgcn_exp2f)
#define EXP2(x) __builtin_amdgcn_exp2f(x)
#else
#define EXP2(x) exp2f(x)
#endif

union PK { fp16x2 v; unsigned int u; };

__device__ __forceinline__ half8 pack8(float a, float b, float c, float d,
                                       float e, float f, float g, float h) {
#if __has_builtin(__builtin_amdgcn_cvt_pkrtz)
    union { unsigned int u[4]; half8 h8; } r;
    PK p0, p1, p2, p3;
    p0.v = __builtin_amdgcn_cvt_pkrtz(a, b);
    p1.v = __builtin_amdgcn_cvt_pkrtz(c, d);
    p2.v = __builtin_amdgcn_cvt_pkrtz(e, f);
    p3.v = __builtin_amdgcn_cvt_pkrtz(g, h);
    r.u[0] = p0.u; r.u[1] = p1.u; r.u[2] = p2.u; r.u[3] = p3.u;
    return r.h8;
#else
    half8 r = { (f16)a, (f16)b, (f16)c, (f16)d, (f16)e, (f16)f, (f16)g, (f16)h };
    return r;
#endif
}

// ---- workspace layout ----
#define WS_KROT 0ull                              // f16 [32][J/32][512]  8,912,896 B (MFMA-frag tile order)
#define WS_VT   8912896ull                        // f16 [32][16][J]      8,912,896 B
#define WS_QROT 17825792ull                       // f16 [32][512][16]      524,288 B
#define WS_HV   18350080ull                       // f16 [2048][128]        524,288 B
#define WS_XN   18874368ull                       // f16 [2048][128]        524,288 B (dies after proj)

union V4  { f16 h[4];  uint2 u; };

__device__ __forceinline__ half8 cvt8(const float* p) {
    float4 a = *(const float4*)p, b = *(const float4*)(p + 4);
    half8 h = { (f16)a.x, (f16)a.y, (f16)a.z, (f16)a.w,
                (f16)b.x, (f16)b.y, (f16)b.z, (f16)b.w };
    return h;
}

// ---------------------------------------------------------------------------
// Kernel 1: LN1 -> xn16 (f16). 512 blocks x 256 thr (1 token/wave).
// Separate so proj's only dependency finishes in ~2 us (R4-best config;
// fusing LN into proj waves measured +1.7us - duplicated LN 24x).
// ---------------------------------------------------------------------------
__global__ void __launch_bounds__(256) ln_kernel(
    const float* __restrict__ x, const float* __restrict__ g1,
    const float* __restrict__ b1, f16* __restrict__ xn16)
{
    int wave = threadIdx.x >> 6, lane = threadIdx.x & 63;
    int token = blockIdx.x * 4 + wave;
    float v0 = x[(size_t)token * DIM + lane];
    float v1 = x[(size_t)token * DIM + lane + 64];
    float s = v0 + v1;
    for (int off = 32; off; off >>= 1) s += __shfl_xor(s, off, 64);
    float mu = s * (1.0f / DIM);
    float d0 = v0 - mu, d1 = v1 - mu;
    float vs = d0 * d0 + d1 * d1;
    for (int off = 32; off; off >>= 1) vs += __shfl_xor(vs, off, 64);
    float rs = rsqrtf(vs * (1.0f / DIM) + 1e-5f);
    xn16[(size_t)token * DIM + lane]      = (f16)(d0 * rs * g1[lane]      + b1[lane]);
    xn16[(size_t)token * DIM + lane + 64] = (f16)(d1 * rs * g1[lane + 64] + b1[lane + 64]);
}

// ---------------------------------------------------------------------------
// Kernel 2: merged {proj GEMM (blocks 0..767)} + {prepKV (blocks 768..4863)}.
// The two halves are independent and fill complementary pipes: prepKV is
// HBM-BW-bound, proj is MFMA/latency-bound -> cost ~ max, not sum.
// prepKV copy uses nontemporal load+store (single-use stream; keeps krot/vt
// L2-resident for attn).
// ---------------------------------------------------------------------------
__global__ void __launch_bounds__(256) prep_proj_kernel(
    const f32x4* __restrict__ src, float4* __restrict__ dstv,
    f16* __restrict__ krot, f16* __restrict__ vt,
    const f16* __restrict__ xn16, const float* __restrict__ wq,
    const float* __restrict__ wkv, f16* __restrict__ qrot)
{
    __shared__ __attribute__((aligned(16))) char smem[8448];

    if (blockIdx.x < 768) {                 // ================= proj =================
        float* out_mem = (float*)dstv;
        int id = blockIdx.x * 4 + (threadIdx.x >> 6);
        int lane = threadIdx.x & 63;
        int ttile = id & 127, ctile = id >> 7;
        int token0 = ttile * 16;
        int col = lane & 15, quad = lane >> 4;

        const float* wbase = (ctile < 8) ? (wq + (size_t)(ctile * 16 + col) * DIM)
                                         : (wkv + (size_t)((ctile - 8) * 16 + col) * DIM);
        const f16* abase = xn16 + (size_t)(token0 + col) * DIM + quad * 8;

        f32x4 acc = {0.f, 0.f, 0.f, 0.f};
        #pragma unroll
        for (int kb = 0; kb < 4; kb++) {
            half8 a = *(const half8*)(abase + kb * 32);
            half8 w = cvt8(wbase + kb * 32 + quad * 8);
            acc = __builtin_amdgcn_mfma_f32_16x16x32_f16(a, w, acc, 0, 0, 0);
        }

        int e = col, r8 = e & 7;
        float f = __expf(-(float)r8 * LN10000_DIV8);
        int kt = ctile - 8;
        int head = (ctile < 8) ? ctile : (kt >> 1);
        int isV  = (ctile >= 8) ? (kt & 1) : 0;

        #pragma unroll
        for (int r = 0; r < 4; r++) {
            int tok = token0 + quad * 4 + r;
            int b = tok >> 9, i = tok & (N - 1);
            int bhh = b * H + head;
            float self = acc[r];
            float prt = __shfl_xor(self, 8, 64);  // partner dim e^8, same token

            if (ctile < 8) {                      // Q: rotary + scale (incl. log2e)
                float ang = (float)(M + i) * f;
                float sn, cs; __sincosf(ang, &sn, &cs);
                float rv = (self * cs + ((e < 8) ? -prt : prt) * sn) * (0.25f * LOG2E);
                qrot[((size_t)bhh * N + i) * 16 + e] = (f16)rv;
            } else if (!isV) {                    // K: fp32 append + repacked rotated fp16
                out_mem[((size_t)bhh * J + M + i) * 32 + e] = self;
                float ang = (float)(M + i) * f;
                float sn, cs; __sincosf(ang, &sn, &cs);
                float rv = self * cs + ((e < 8) ? -prt : prt) * sn;
                int jpos = M + i;
                int tilei = jpos >> 5, jj = jpos & 31;
                int col4 = (jj >> 3) * 4 + (jj & 3), frag = (jj >> 2) & 1;
                krot[(size_t)bhh * J * 16 + (size_t)tilei * 512 +
                     (e >> 2) * 128 + col4 * 8 + frag * 4 + (e & 3)] = (f16)rv;
            } else {                              // V: fp32 append + fp16 V^T
                out_mem[((size_t)bhh * J + M + i) * 32 + 16 + e] = self;
                vt[(size_t)bhh * 16 * J + (size_t)e * J + M + i] = (f16)self;
            }
        }
    } else {                                // ================ prepKV ================
        float (*tile)[33] = (float (*)[33])smem;
        int bid = blockIdx.x - 768;
        int bh = bid >> 7;
        int j0 = (bid & 127) * 64;
        int t = threadIdx.x;

        #pragma unroll
        for (int rep = 0; rep < 2; rep++) {
            int idx = t + rep * 256;
            int row = idx >> 3, c4 = idx & 7;
            f32x4 v = __builtin_nontemporal_load(src + ((size_t)bh * M + j0 + row) * 8 + c4);
            __builtin_nontemporal_store(v,
                (f32x4*)dstv + ((size_t)bh * J + j0 + row) * 8 + c4);
            tile[row][c4 * 4 + 0] = v[0]; tile[row][c4 * 4 + 1] = v[1];
            tile[row][c4 * 4 + 2] = v[2]; tile[row][c4 * 4 + 3] = v[3];
        }
        __syncthreads();

        if (t < 128) {                      // rotated K: 2 threads/row, 4 sincos each
            int row = t >> 1, rh = t & 1;
            int j = j0 + row;
            float lo4[4], hi4[4];
            #pragma unroll
            for (int i = 0; i < 4; i++) {
                int r = rh * 4 + i;
                float ang = (float)j * __expf(-(float)r * LN10000_DIV8);
                float sn, cs; __sincosf(ang, &sn, &cs);
                float lo = tile[row][r], hi = tile[row][r + 8];
                lo4[i] = lo * cs - hi * sn;
                hi4[i] = hi * cs + lo * sn;
            }
            int tilei = j >> 5, jj = j & 31;
            int col4 = (jj >> 3) * 4 + (jj & 3), frag = (jj >> 2) & 1;
            f16* base = krot + (size_t)bh * J * 16 + (size_t)tilei * 512 + col4 * 8 + frag * 4;
            V4 wl, wh;
            #pragma unroll
            for (int i = 0; i < 4; i++) { wl.h[i] = (f16)lo4[i]; wh.h[i] = (f16)hi4[i]; }
            *(uint2*)(base + rh * 128)       = wl.u;   // dims rh*4 .. rh*4+3
            *(uint2*)(base + (2 + rh) * 128) = wh.u;   // dims 8+rh*4 .. 8+rh*4+3
        }
        {                                   // V^T: dh-major, j contiguous
            int dh = t >> 4, c0 = (t & 15) * 4;
            V4 vv;
            #pragma unroll
            for (int i = 0; i < 4; i++) vv.h[i] = (f16)tile[c0 + i][16 + dh];
            *(uint2*)(vt + (size_t)bh * 16 * J + (size_t)dh * J + j0 + c0) = vv.u;
        }
    }
}

// ---------------------------------------------------------------------------
// Kernel 3: MFMA flash attention (R4's proven 23us kernel, verbatim).
// grid = 512 blocks (32 bh low-bits -> XCD-local L2 reuse, 16 qgroups of 32q)
// x 1024 threads = 16 waves -> 32 waves/CU ceiling. Each wave: 2 q-tiles,
// J/16 = 544 keys (17 iters). Softmax denominator on the MFMA pipe via
// all-ones B operand. Output reduction spread over 512 threads.
// ---------------------------------------------------------------------------
__global__ void __launch_bounds__(1024) attn_kernel(
    const f16* __restrict__ krot, const f16* __restrict__ vt,
    const f16* __restrict__ qrot, f16* __restrict__ hvw)
{
    __shared__ float sacc[16][2][256];
    __shared__ float sl[16][2][16];
    int bh = blockIdx.x & 31;               // same-bh blocks -> same XCD
    int q0 = (blockIdx.x >> 5) * 32;
    int wave = threadIdx.x >> 6, lane = threadIdx.x & 63;
    int col = lane & 15, quad = lane >> 4;

    const f16* vb = vt + (size_t)bh * 16 * J + (size_t)col * J;
    half4 qfa = *(const half4*)(qrot + ((size_t)bh * N + q0 + col) * 16 + quad * 4);
    half4 qfb = *(const half4*)(qrot + ((size_t)bh * N + q0 + 16 + col) * 16 + quad * 4);

    int jstart = wave * (J / 16);           // 544 = 17 iters of 32 keys
    const f16* kptr = krot + (size_t)bh * J * 16 + (size_t)jstart * 16 + lane * 8;
    const f16* vptr = vb + jstart + quad * 8;

    f32x4 acca = {0.f, 0.f, 0.f, 0.f};
    f32x4 accb = {0.f, 0.f, 0.f, 0.f};
    f32x4 accla = {0.f, 0.f, 0.f, 0.f};
    f32x4 acclb = {0.f, 0.f, 0.f, 0.f};
    const f32x4 zero = {0.f, 0.f, 0.f, 0.f};
    const half8 ones = { (f16)1.f, (f16)1.f, (f16)1.f, (f16)1.f,
                         (f16)1.f, (f16)1.f, (f16)1.f, (f16)1.f };

    #pragma unroll 2
    for (int it = 0; it < 17; ++it) {
        half8 kf8 = *(const half8*)kptr;
        half8 vf  = *(const half8*)vptr;
        kptr += 512; vptr += 32;
        half4 kf0 = __builtin_shufflevector(kf8, kf8, 0, 1, 2, 3);
        half4 kf1 = __builtin_shufflevector(kf8, kf8, 4, 5, 6, 7);
        f32x4 s0a = __builtin_amdgcn_mfma_f32_16x16x16f16(kf0, qfa, zero, 0, 0, 0);
        f32x4 s1a = __builtin_amdgcn_mfma_f32_16x16x16f16(kf1, qfa, zero, 0, 0, 0);
        f32x4 s0b = __builtin_amdgcn_mfma_f32_16x16x16f16(kf0, qfb, zero, 0, 0, 0);
        f32x4 s1b = __builtin_amdgcn_mfma_f32_16x16x16f16(kf1, qfb, zero, 0, 0, 0);

        float a0 = EXP2(s0a[0]), a1 = EXP2(s0a[1]), a2 = EXP2(s0a[2]), a3 = EXP2(s0a[3]);
        float a4 = EXP2(s1a[0]), a5 = EXP2(s1a[1]), a6 = EXP2(s1a[2]), a7 = EXP2(s1a[3]);
        float b0 = EXP2(s0b[0]), b1 = EXP2(s0b[1]), b2 = EXP2(s0b[2]), b3 = EXP2(s0b[3]);
        float b4 = EXP2(s1b[0]), b5 = EXP2(s1b[1]), b6 = EXP2(s1b[2]), b7 = EXP2(s1b[3]);
        half8 pfa = pack8(a0, a1, a2, a3, a4, a5, a6, a7);
        half8 pfb = pack8(b0, b1, b2, b3, b4, b5, b6, b7);
        acca  = __builtin_amdgcn_mfma_f32_16x16x32_f16(pfa, vf,   acca,  0, 0, 0);
        accla = __builtin_amdgcn_mfma_f32_16x16x32_f16(pfa, ones, accla, 0, 0, 0);
        accb  = __builtin_amdgcn_mfma_f32_16x16x32_f16(pfb, vf,   accb,  0, 0, 0);
        acclb = __builtin_amdgcn_mfma_f32_16x16x32_f16(pfb, ones, acclb, 0, 0, 0);
    }

    if (col == 0) {                         // l row-sums live in every col of accl*
        #pragma unroll
        for (int r = 0; r < 4; r++) {
            sl[wave][0][quad * 4 + r] = accla[r];
            sl[wave][1][quad * 4 + r] = acclb[r];
        }
    }
    #pragma unroll
    for (int r = 0; r < 4; r++) {
        sacc[wave][0][(quad * 4 + r) * 16 + col] = acca[r];
        sacc[wave][1][(quad * 4 + r) * 16 + col] = accb[r];
    }
    __syncthreads();

    if (threadIdx.x < 512) {                // 512 outputs -> 512 threads (8 waves)
        int t = threadIdx.x;
        int qt = t >> 8, ql = (t >> 4) & 15, c = t & 15;
        float o = 0.f, lt = 0.f;
        #pragma unroll
        for (int w = 0; w < 16; w++) {
            o  += sacc[w][qt][ql * 16 + c];
            lt += sl[w][qt][ql];
        }
        int b = bh >> 3, h = bh & 7;
        hvw[((size_t)(b * N) + q0 + qt * 16 + ql) * DIM + h * DH + c] = (f16)(o / lt);
    }
}

// ---------------------------------------------------------------------------
// Kernel 4: fused residual + LN2 + MFMA out-proj + residual.
// grid = 256 blocks (16 tokens, 4 of 8 col-tiles each; LN duplicated x2),
// 256 thr = 4 waves.
// ---------------------------------------------------------------------------
__global__ void __launch_bounds__(256) final_kernel(
    const f16* __restrict__ hvw, const float* __restrict__ x,
    const float* __restrict__ wout, const float* __restrict__ bout,
    const float* __restrict__ g2, const float* __restrict__ b2v,
    float* __restrict__ out)
{
    __shared__ f16 xn2[16][136];
    __shared__ float hres[16][132];
    int token0 = (blockIdx.x >> 1) * 16;
    int half = blockIdx.x & 1;
    int wave = threadIdx.x >> 6, lane = threadIdx.x & 63;

    #pragma unroll
    for (int tt = 0; tt < 4; tt++) {
        int tl = wave * 4 + tt;
        int token = token0 + tl;
        float h0 = (float)hvw[(size_t)token * DIM + lane]      + x[(size_t)token * DIM + lane];
        float h1 = (float)hvw[(size_t)token * DIM + lane + 64] + x[(size_t)token * DIM + lane + 64];
        float s = h0 + h1;
        for (int off = 32; off; off >>= 1) s += __shfl_xor(s, off, 64);
        float mu = s * (1.0f / DIM);
        float d0 = h0 - mu, d1 = h1 - mu;
        float vs = d0 * d0 + d1 * d1;
        for (int off = 32; off; off >>= 1) vs += __shfl_xor(vs, off, 64);
        float rs = rsqrtf(vs * (1.0f / DIM) + 1e-5f);
        xn2[tl][lane]      = (f16)(d0 * rs * g2[lane]      + b2v[lane]);
        xn2[tl][lane + 64] = (f16)(d1 * rs * g2[lane + 64] + b2v[lane + 64]);
        hres[tl][lane] = h0; hres[tl][lane + 64] = h1;
    }
    __syncthreads();

    int col = lane & 15, quad = lane >> 4;
    int ct = half * 4 + wave;               // this block's 4 col-tiles
    int cg = ct * 16 + col;
    const float* wrow = wout + (size_t)cg * DIM;
    f32x4 acc = {0.f, 0.f, 0.f, 0.f};
    #pragma unroll
    for (int kb = 0; kb < 4; kb++) {
        half8 a = *(const half8*)(&xn2[col][kb * 32 + quad * 8]);
        half8 w = cvt8(wrow + kb * 32 + quad * 8);
        acc = __builtin_amdgcn_mfma_f32_16x16x32_f16(a, w, acc, 0, 0, 0);
    }
    float bo = bout[cg];
    #pragma unroll
    for (int r = 0; r < 4; r++) {
        int tl = quad * 4 + r;
        out[(size_t)(token0 + tl) * DIM + cg] = acc[r] + bo + hres[tl][cg];
    }
}

// ===========================================================================
extern "C" void kernel_launch(void* const* d_in, const int* in_sizes, int n_in,
                              void* d_out, int out_size, void* d_ws, size_t ws_size,
                              hipStream_t stream)
{
    const float* x      = (const float*)d_in[0];
    const float* mem_kv = (const float*)d_in[1];
    const float* wq     = (const float*)d_in[2];
    const float* wkv    = (const float*)d_in[3];
    const float* wout   = (const float*)d_in[4];
    const float* bout   = (const float*)d_in[5];
    const float* g1     = (const float*)d_in[6];
    const float* b1     = (const float*)d_in[7];
    const float* g2     = (const float*)d_in[8];
    const float* b2     = (const float*)d_in[9];

    float* out = (float*)d_out;
    float* out_mem = out + (size_t)B * N * DIM;

    f16* krot = (f16*)((char*)d_ws + WS_KROT);
    f16* vt   = (f16*)((char*)d_ws + WS_VT);
    f16* qrot = (f16*)((char*)d_ws + WS_QROT);
    f16* hvw  = (f16*)((char*)d_ws + WS_HV);
    f16* xn16 = (f16*)((char*)d_ws + WS_XN);

    hipLaunchKernelGGL(ln_kernel, dim3(512), dim3(256), 0, stream,
                       x, g1, b1, xn16);
    hipLaunchKernelGGL(prep_proj_kernel, dim3(4864), dim3(256), 0, stream,
                       (const f32x4*)mem_kv, (float4*)out_mem, krot, vt,
                       xn16, wq, wkv, qrot);
    hipLaunchKernelGGL(attn_kernel, dim3(512), dim3(1024), 0, stream,
                       krot, vt, qrot, hvw);
    hipLaunchKernelGGL(final_kernel, dim3(256), dim3(256), 0, stream,
                       hvw, x, wout, bout, g2, b2, out);
}

// Round 12
// 139.809 us; speedup vs baseline: 1.5236x; 1.0260x over previous
//
#include <hip/hip_runtime.h>

#define B 4
#define N 512
#define M 8192
#define H 8
#define DH 16
#define DIM 128
#define J (M + N)          // 8704
#define LN10000_DIV8 1.1512925465f   // ln(10000)/8
#define LOG2E 1.44269504f

typedef _Float16 f16;
typedef _Float16 half4 __attribute__((ext_vector_type(4)));
typedef _Float16 half8 __attribute__((ext_vector_type(8)));
typedef __fp16 fp16x2 __attribute__((ext_vector_type(2)));
typedef float f32x4 __attribute__((ext_vector_type(4)));

#if __has_builtin(__builtin_amdgcn_exp2f)
#define EXP2(x) __builtin_amdgcn_exp2f(x)
#else
#define EXP2(x) exp2f(x)
#endif

union PK { fp16x2 v; unsigned int u; };

__device__ __forceinline__ half8 pack8(float a, float b, float c, float d,
                                       float e, float f, float g, float h) {
#if __has_builtin(__builtin_amdgcn_cvt_pkrtz)
    union { unsigned int u[4]; half8 h8; } r;
    PK p0, p1, p2, p3;
    p0.v = __builtin_amdgcn_cvt_pkrtz(a, b);
    p1.v = __builtin_amdgcn_cvt_pkrtz(c, d);
    p2.v = __builtin_amdgcn_cvt_pkrtz(e, f);
    p3.v = __builtin_amdgcn_cvt_pkrtz(g, h);
    r.u[0] = p0.u; r.u[1] = p1.u; r.u[2] = p2.u; r.u[3] = p3.u;
    return r.h8;
#else
    half8 r = { (f16)a, (f16)b, (f16)c, (f16)d, (f16)e, (f16)f, (f16)g, (f16)h };
    return r;
#endif
}

// ---- workspace layout ----
#define WS_KROT 0ull                              // f16 [32][J/32][512]  8,912,896 B (MFMA-frag tile order)
#define WS_VT   8912896ull                        // f16 [32][16][J]      8,912,896 B
#define WS_QROT 17825792ull                       // f16 [32][512][16]      524,288 B
#define WS_HV   18350080ull                       // f16 [2048][128]        524,288 B
#define WS_XN   18874368ull                       // f16 [2048][128]        524,288 B (dies after proj)

union V4  { f16 h[4];  uint2 u; };

__device__ __forceinline__ half8 cvt8(const float* p) {
    float4 a = *(const float4*)p, b = *(const float4*)(p + 4);
    half8 h = { (f16)a.x, (f16)a.y, (f16)a.z, (f16)a.w,
                (f16)b.x, (f16)b.y, (f16)b.z, (f16)b.w };
    return h;
}

// ---------------------------------------------------------------------------
// Kernel 1: LN1 -> xn16 (f16). 512 blocks x 256 thr (1 token/wave).
// Separate so proj's only dependency finishes in ~2 us (R4-best config).
// ---------------------------------------------------------------------------
__global__ void __launch_bounds__(256) ln_kernel(
    const float* __restrict__ x, const float* __restrict__ g1,
    const float* __restrict__ b1, f16* __restrict__ xn16)
{
    int wave = threadIdx.x >> 6, lane = threadIdx.x & 63;
    int token = blockIdx.x * 4 + wave;
    float v0 = x[(size_t)token * DIM + lane];
    float v1 = x[(size_t)token * DIM + lane + 64];
    float s = v0 + v1;
    for (int off = 32; off; off >>= 1) s += __shfl_xor(s, off, 64);
    float mu = s * (1.0f / DIM);
    float d0 = v0 - mu, d1 = v1 - mu;
    float vs = d0 * d0 + d1 * d1;
    for (int off = 32; off; off >>= 1) vs += __shfl_xor(vs, off, 64);
    float rs = rsqrtf(vs * (1.0f / DIM) + 1e-5f);
    xn16[(size_t)token * DIM + lane]      = (f16)(d0 * rs * g1[lane]      + b1[lane]);
    xn16[(size_t)token * DIM + lane + 64] = (f16)(d1 * rs * g1[lane + 64] + b1[lane + 64]);
}

// ---------------------------------------------------------------------------
// Kernel 2: merged {proj GEMM (blocks 0..767)} + {prepKV (blocks 768..4863)}.
// The two halves are independent and fill complementary pipes: prepKV is
// HBM-BW-bound, proj is MFMA/latency-bound -> cost ~ max, not sum.
// Copy uses PLAIN load/store: R11 A/B showed nontemporal hints cost ~5us
// (no-allocate write-through loses L2 write-coalescing on the 67MB stream).
// ---------------------------------------------------------------------------
__global__ void __launch_bounds__(256) prep_proj_kernel(
    const float4* __restrict__ src, float4* __restrict__ dstv,
    f16* __restrict__ krot, f16* __restrict__ vt,
    const f16* __restrict__ xn16, const float* __restrict__ wq,
    const float* __restrict__ wkv, f16* __restrict__ qrot)
{
    __shared__ __attribute__((aligned(16))) char smem[8448];

    if (blockIdx.x < 768) {                 // ================= proj =================
        float* out_mem = (float*)dstv;
        int id = blockIdx.x * 4 + (threadIdx.x >> 6);
        int lane = threadIdx.x & 63;
        int ttile = id & 127, ctile = id >> 7;
        int token0 = ttile * 16;
        int col = lane & 15, quad = lane >> 4;

        const float* wbase = (ctile < 8) ? (wq + (size_t)(ctile * 16 + col) * DIM)
                                         : (wkv + (size_t)((ctile - 8) * 16 + col) * DIM);
        const f16* abase = xn16 + (size_t)(token0 + col) * DIM + quad * 8;

        f32x4 acc = {0.f, 0.f, 0.f, 0.f};
        #pragma unroll
        for (int kb = 0; kb < 4; kb++) {
            half8 a = *(const half8*)(abase + kb * 32);
            half8 w = cvt8(wbase + kb * 32 + quad * 8);
            acc = __builtin_amdgcn_mfma_f32_16x16x32_f16(a, w, acc, 0, 0, 0);
        }

        int e = col, r8 = e & 7;
        float f = __expf(-(float)r8 * LN10000_DIV8);
        int kt = ctile - 8;
        int head = (ctile < 8) ? ctile : (kt >> 1);
        int isV  = (ctile >= 8) ? (kt & 1) : 0;

        #pragma unroll
        for (int r = 0; r < 4; r++) {
            int tok = token0 + quad * 4 + r;
            int b = tok >> 9, i = tok & (N - 1);
            int bhh = b * H + head;
            float self = acc[r];
            float prt = __shfl_xor(self, 8, 64);  // partner dim e^8, same token

            if (ctile < 8) {                      // Q: rotary + scale (incl. log2e)
                float ang = (float)(M + i) * f;
                float sn, cs; __sincosf(ang, &sn, &cs);
                float rv = (self * cs + ((e < 8) ? -prt : prt) * sn) * (0.25f * LOG2E);
                qrot[((size_t)bhh * N + i) * 16 + e] = (f16)rv;
            } else if (!isV) {                    // K: fp32 append + repacked rotated fp16
                out_mem[((size_t)bhh * J + M + i) * 32 + e] = self;
                float ang = (float)(M + i) * f;
                float sn, cs; __sincosf(ang, &sn, &cs);
                float rv = self * cs + ((e < 8) ? -prt : prt) * sn;
                int jpos = M + i;
                int tilei = jpos >> 5, jj = jpos & 31;
                int col4 = (jj >> 3) * 4 + (jj & 3), frag = (jj >> 2) & 1;
                krot[(size_t)bhh * J * 16 + (size_t)tilei * 512 +
                     (e >> 2) * 128 + col4 * 8 + frag * 4 + (e & 3)] = (f16)rv;
            } else {                              // V: fp32 append + fp16 V^T
                out_mem[((size_t)bhh * J + M + i) * 32 + 16 + e] = self;
                vt[(size_t)bhh * 16 * J + (size_t)e * J + M + i] = (f16)self;
            }
        }
    } else {                                // ================ prepKV ================
        float (*tile)[33] = (float (*)[33])smem;
        int bid = blockIdx.x - 768;
        int bh = bid >> 7;
        int j0 = (bid & 127) * 64;
        int t = threadIdx.x;

        #pragma unroll
        for (int rep = 0; rep < 2; rep++) {
            int idx = t + rep * 256;
            int row = idx >> 3, c4 = idx & 7;
            float4 v = src[((size_t)bh * M + j0 + row) * 8 + c4];
            dstv[((size_t)bh * J + j0 + row) * 8 + c4] = v;
            tile[row][c4 * 4 + 0] = v.x; tile[row][c4 * 4 + 1] = v.y;
            tile[row][c4 * 4 + 2] = v.z; tile[row][c4 * 4 + 3] = v.w;
        }
        __syncthreads();

        if (t < 128) {                      // rotated K: 2 threads/row, 4 sincos each
            int row = t >> 1, rh = t & 1;
            int j = j0 + row;
            float lo4[4], hi4[4];
            #pragma unroll
            for (int i = 0; i < 4; i++) {
                int r = rh * 4 + i;
                float ang = (float)j * __expf(-(float)r * LN10000_DIV8);
                float sn, cs; __sincosf(ang, &sn, &cs);
                float lo = tile[row][r], hi = tile[row][r + 8];
                lo4[i] = lo * cs - hi * sn;
                hi4[i] = hi * cs + lo * sn;
            }
            int tilei = j >> 5, jj = j & 31;
            int col4 = (jj >> 3) * 4 + (jj & 3), frag = (jj >> 2) & 1;
            f16* base = krot + (size_t)bh * J * 16 + (size_t)tilei * 512 + col4 * 8 + frag * 4;
            V4 wl, wh;
            #pragma unroll
            for (int i = 0; i < 4; i++) { wl.h[i] = (f16)lo4[i]; wh.h[i] = (f16)hi4[i]; }
            *(uint2*)(base + rh * 128)       = wl.u;   // dims rh*4 .. rh*4+3
            *(uint2*)(base + (2 + rh) * 128) = wh.u;   // dims 8+rh*4 .. 8+rh*4+3
        }
        {                                   // V^T: dh-major, j contiguous
            int dh = t >> 4, c0 = (t & 15) * 4;
            V4 vv;
            #pragma unroll
            for (int i = 0; i < 4; i++) vv.h[i] = (f16)tile[c0 + i][16 + dh];
            *(uint2*)(vt + (size_t)bh * 16 * J + (size_t)dh * J + j0 + c0) = vv.u;
        }
    }
}

// ---------------------------------------------------------------------------
// Kernel 3: MFMA flash attention (R4's proven 23us kernel, verbatim).
// grid = 512 blocks (32 bh low-bits -> XCD-local L2 reuse, 16 qgroups of 32q)
// x 1024 threads = 16 waves -> 32 waves/CU ceiling. Each wave: 2 q-tiles,
// J/16 = 544 keys (17 iters). Softmax denominator on the MFMA pipe via
// all-ones B operand. Output reduction spread over 512 threads.
// ---------------------------------------------------------------------------
__global__ void __launch_bounds__(1024) attn_kernel(
    const f16* __restrict__ krot, const f16* __restrict__ vt,
    const f16* __restrict__ qrot, f16* __restrict__ hvw)
{
    __shared__ float sacc[16][2][256];
    __shared__ float sl[16][2][16];
    int bh = blockIdx.x & 31;               // same-bh blocks -> same XCD
    int q0 = (blockIdx.x >> 5) * 32;
    int wave = threadIdx.x >> 6, lane = threadIdx.x & 63;
    int col = lane & 15, quad = lane >> 4;

    const f16* vb = vt + (size_t)bh * 16 * J + (size_t)col * J;
    half4 qfa = *(const half4*)(qrot + ((size_t)bh * N + q0 + col) * 16 + quad * 4);
    half4 qfb = *(const half4*)(qrot + ((size_t)bh * N + q0 + 16 + col) * 16 + quad * 4);

    int jstart = wave * (J / 16);           // 544 = 17 iters of 32 keys
    const f16* kptr = krot + (size_t)bh * J * 16 + (size_t)jstart * 16 + lane * 8;
    const f16* vptr = vb + jstart + quad * 8;

    f32x4 acca = {0.f, 0.f, 0.f, 0.f};
    f32x4 accb = {0.f, 0.f, 0.f, 0.f};
    f32x4 accla = {0.f, 0.f, 0.f, 0.f};
    f32x4 acclb = {0.f, 0.f, 0.f, 0.f};
    const f32x4 zero = {0.f, 0.f, 0.f, 0.f};
    const half8 ones = { (f16)1.f, (f16)1.f, (f16)1.f, (f16)1.f,
                         (f16)1.f, (f16)1.f, (f16)1.f, (f16)1.f };

    #pragma unroll 2
    for (int it = 0; it < 17; ++it) {
        half8 kf8 = *(const half8*)kptr;
        half8 vf  = *(const half8*)vptr;
        kptr += 512; vptr += 32;
        half4 kf0 = __builtin_shufflevector(kf8, kf8, 0, 1, 2, 3);
        half4 kf1 = __builtin_shufflevector(kf8, kf8, 4, 5, 6, 7);
        f32x4 s0a = __builtin_amdgcn_mfma_f32_16x16x16f16(kf0, qfa, zero, 0, 0, 0);
        f32x4 s1a = __builtin_amdgcn_mfma_f32_16x16x16f16(kf1, qfa, zero, 0, 0, 0);
        f32x4 s0b = __builtin_amdgcn_mfma_f32_16x16x16f16(kf0, qfb, zero, 0, 0, 0);
        f32x4 s1b = __builtin_amdgcn_mfma_f32_16x16x16f16(kf1, qfb, zero, 0, 0, 0);

        float a0 = EXP2(s0a[0]), a1 = EXP2(s0a[1]), a2 = EXP2(s0a[2]), a3 = EXP2(s0a[3]);
        float a4 = EXP2(s1a[0]), a5 = EXP2(s1a[1]), a6 = EXP2(s1a[2]), a7 = EXP2(s1a[3]);
        float b0 = EXP2(s0b[0]), b1 = EXP2(s0b[1]), b2 = EXP2(s0b[2]), b3 = EXP2(s0b[3]);
        float b4 = EXP2(s1b[0]), b5 = EXP2(s1b[1]), b6 = EXP2(s1b[2]), b7 = EXP2(s1b[3]);
        half8 pfa = pack8(a0, a1, a2, a3, a4, a5, a6, a7);
        half8 pfb = pack8(b0, b1, b2, b3, b4, b5, b6, b7);
        acca  = __builtin_amdgcn_mfma_f32_16x16x32_f16(pfa, vf,   acca,  0, 0, 0);
        accla = __builtin_amdgcn_mfma_f32_16x16x32_f16(pfa, ones, accla, 0, 0, 0);
        accb  = __builtin_amdgcn_mfma_f32_16x16x32_f16(pfb, vf,   accb,  0, 0, 0);
        acclb = __builtin_amdgcn_mfma_f32_16x16x32_f16(pfb, ones, acclb, 0, 0, 0);
    }

    if (col == 0) {                         // l row-sums live in every col of accl*
        #pragma unroll
        for (int r = 0; r < 4; r++) {
            sl[wave][0][quad * 4 + r] = accla[r];
            sl[wave][1][quad * 4 + r] = acclb[r];
        }
    }
    #pragma unroll
    for (int r = 0; r < 4; r++) {
        sacc[wave][0][(quad * 4 + r) * 16 + col] = acca[r];
        sacc[wave][1][(quad * 4 + r) * 16 + col] = accb[r];
    }
    __syncthreads();

    if (threadIdx.x < 512) {                // 512 outputs -> 512 threads (8 waves)
        int t = threadIdx.x;
        int qt = t >> 8, ql = (t >> 4) & 15, c = t & 15;
        float o = 0.f, lt = 0.f;
        #pragma unroll
        for (int w = 0; w < 16; w++) {
            o  += sacc[w][qt][ql * 16 + c];
            lt += sl[w][qt][ql];
        }
        int b = bh >> 3, h = bh & 7;
        hvw[((size_t)(b * N) + q0 + qt * 16 + ql) * DIM + h * DH + c] = (f16)(o / lt);
    }
}

// ---------------------------------------------------------------------------
// Kernel 4: fused residual + LN2 + MFMA out-proj + residual.
// grid = 256 blocks (16 tokens, 4 of 8 col-tiles each; LN duplicated x2),
// 256 thr = 4 waves.
// ---------------------------------------------------------------------------
__global__ void __launch_bounds__(256) final_kernel(
    const f16* __restrict__ hvw, const float* __restrict__ x,
    const float* __restrict__ wout, const float* __restrict__ bout,
    const float* __restrict__ g2, const float* __restrict__ b2v,
    float* __restrict__ out)
{
    __shared__ f16 xn2[16][136];
    __shared__ float hres[16][132];
    int token0 = (blockIdx.x >> 1) * 16;
    int half = blockIdx.x & 1;
    int wave = threadIdx.x >> 6, lane = threadIdx.x & 63;

    #pragma unroll
    for (int tt = 0; tt < 4; tt++) {
        int tl = wave * 4 + tt;
        int token = token0 + tl;
        float h0 = (float)hvw[(size_t)token * DIM + lane]      + x[(size_t)token * DIM + lane];
        float h1 = (float)hvw[(size_t)token * DIM + lane + 64] + x[(size_t)token * DIM + lane + 64];
        float s = h0 + h1;
        for (int off = 32; off; off >>= 1) s += __shfl_xor(s, off, 64);
        float mu = s * (1.0f / DIM);
        float d0 = h0 - mu, d1 = h1 - mu;
        float vs = d0 * d0 + d1 * d1;
        for (int off = 32; off; off >>= 1) vs += __shfl_xor(vs, off, 64);
        float rs = rsqrtf(vs * (1.0f / DIM) + 1e-5f);
        xn2[tl][lane]      = (f16)(d0 * rs * g2[lane]      + b2v[lane]);
        xn2[tl][lane + 64] = (f16)(d1 * rs * g2[lane + 64] + b2v[lane + 64]);
        hres[tl][lane] = h0; hres[tl][lane + 64] = h1;
    }
    __syncthreads();

    int col = lane & 15, quad = lane >> 4;
    int ct = half * 4 + wave;               // this block's 4 col-tiles
    int cg = ct * 16 + col;
    const float* wrow = wout + (size_t)cg * DIM;
    f32x4 acc = {0.f, 0.f, 0.f, 0.f};
    #pragma unroll
    for (int kb = 0; kb < 4; kb++) {
        half8 a = *(const half8*)(&xn2[col][kb * 32 + quad * 8]);
        half8 w = cvt8(wrow + kb * 32 + quad * 8);
        acc = __builtin_amdgcn_mfma_f32_16x16x32_f16(a, w, acc, 0, 0, 0);
    }
    float bo = bout[cg];
    #pragma unroll
    for (int r = 0; r < 4; r++) {
        int tl = quad * 4 + r;
        out[(size_t)(token0 + tl) * DIM + cg] = acc[r] + bo + hres[tl][cg];
    }
}

// ===========================================================================
extern "C" void kernel_launch(void* const* d_in, const int* in_sizes, int n_in,
                              void* d_out, int out_size, void* d_ws, size_t ws_size,
                              hipStream_t stream)
{
    const float* x      = (const float*)d_in[0];
    const float* mem_kv = (const float*)d_in[1];
    const float* wq     = (const float*)d_in[2];
    const float* wkv    = (const float*)d_in[3];
    const float* wout   = (const float*)d_in[4];
    const float* bout   = (const float*)d_in[5];
    const float* g1     = (const float*)d_in[6];
    const float* b1     = (const float*)d_in[7];
    const float* g2     = (const float*)d_in[8];
    const float* b2     = (const float*)d_in[9];

    float* out = (float*)d_out;
    float* out_mem = out + (size_t)B * N * DIM;

    f16* krot = (f16*)((char*)d_ws + WS_KROT);
    f16* vt   = (f16*)((char*)d_ws + WS_VT);
    f16* qrot = (f16*)((char*)d_ws + WS_QROT);
    f16* hvw  = (f16*)((char*)d_ws + WS_HV);
    f16* xn16 = (f16*)((char*)d_ws + WS_XN);

    hipLaunchKernelGGL(ln_kernel, dim3(512), dim3(256), 0, stream,
                       x, g1, b1, xn16);
    hipLaunchKernelGGL(prep_proj_kernel, dim3(4864), dim3(256), 0, stream,
                       (const float4*)mem_kv, (float4*)out_mem, krot, vt,
                       xn16, wq, wkv, qrot);
    hipLaunchKernelGGL(attn_kernel, dim3(512), dim3(1024), 0, stream,
                       krot, vt, qrot, hvw);
    hipLaunchKernelGGL(final_kernel, dim3(256), dim3(256), 0, stream,
                       hvw, x, wout, bout, g2, b2, out);
}